// Round 1
// baseline (306.090 us; speedup 1.0000x reference)
//
#include <hip/hip_runtime.h>
#include <stdint.h>

// Problem constants
#define BB 2
#define SS 2048
#define DD 1024
#define HH 16
#define DHD 64
#define MM (BB * SS)  // 4096

typedef unsigned short u16;
typedef unsigned int u32;
typedef __attribute__((ext_vector_type(8))) short bhalf8;   // 8 bf16 in 4 VGPRs
typedef __attribute__((ext_vector_type(4))) float floatx4;  // MFMA 16x16 accumulator
typedef __attribute__((address_space(3))) u32 as3_u32;
typedef __attribute__((address_space(1))) u32 as1_u32;

__device__ __forceinline__ u16 f2bf(float f) {
  u32 u = __float_as_uint(f);
  u32 r = (u + 0x7FFFu + ((u >> 16) & 1u)) >> 16;  // RNE
  return (u16)r;
}

// async global->LDS, 16B per lane; lds dest must be wave-uniform base (+lane*16 by HW)
__device__ __forceinline__ void gload16(const void* g, const void* l) {
  __builtin_amdgcn_global_load_lds((as1_u32*)(uintptr_t)g, (as3_u32*)(uintptr_t)l, 16, 0, 0);
}

// ---------------- fp32 -> bf16 elementwise convert (vectorized x4) ----------------
__global__ void k_convert(const float* __restrict__ in, u16* __restrict__ out, int n4) {
  int i = blockIdx.x * 256 + threadIdx.x;
  if (i < n4) {
    float4 v = ((const float4*)in)[i];
    ushort4 o;
    o.x = f2bf(v.x); o.y = f2bf(v.y); o.z = f2bf(v.z); o.w = f2bf(v.w);
    ((ushort4*)out)[i] = o;
  }
}

// ---------------- W[K][N] fp32 -> Wt[N][K] bf16 (tiled transpose) ----------------
__global__ void k_transpose_w(const float* __restrict__ W, u16* __restrict__ Wt) {
  __shared__ u16 tile[32][33];
  const int tx = threadIdx.x, ty = threadIdx.y;  // (32, 8)
  const int n0 = blockIdx.x * 32, k0 = blockIdx.y * 32;
#pragma unroll
  for (int i = 0; i < 4; ++i)
    tile[ty + 8 * i][tx] = f2bf(W[(size_t)(k0 + ty + 8 * i) * DD + n0 + tx]);
  __syncthreads();
#pragma unroll
  for (int i = 0; i < 4; ++i)
    Wt[(size_t)(n0 + ty + 8 * i) * DD + k0 + tx] = tile[tx][ty + 8 * i];
}

// ---------------- bf16 GEMM: C = A[M][K] * Bt[N][K]^T ----------------
// 128x128 tile, BK=32, 4 waves (2x2), 16x16x32 MFMA, global_load_lds double-buffer.
// MODE 0: bf16 C[M][N] row-major, scaled.  MODE 1: bf16 head-transposed V^T.
// MODE 2: fp32 C[M][N] row-major.
template <int MODE>
__global__ __launch_bounds__(256, 2) void k_gemm_bt(
    const u16* __restrict__ A, const u16* __restrict__ Bt, void* __restrict__ Cout,
    const int Ndim, const int Kdim, const float scale) {
  __shared__ __attribute__((aligned(16))) u16 sA[2][128 * 32];
  __shared__ __attribute__((aligned(16))) u16 sB[2][128 * 32];
  const int t = threadIdx.x;
  const int w = t >> 6, lane = t & 63;
  const int lr = lane & 15, lg = lane >> 4;
  const int wr = w >> 1, wc = w & 1;
  const int row0 = blockIdx.y * 128, col0 = blockIdx.x * 128;

  const int srow = t >> 2;         // staging row 0..63
  const int skoff = (t & 3) * 8;   // staging k element offset
  const u16* gA = A + (size_t)(row0 + srow) * Kdim + skoff;
  const u16* gB = Bt + (size_t)(col0 + srow) * Kdim + skoff;
  const int ldsbase = w * 512;     // wave-uniform LDS element base

  floatx4 acc[4][4] = {};

  auto stage = [&](int buf, int kt) {
    const int ko = kt * 32;
    gload16(gA + ko, &sA[buf][ldsbase]);
    gload16(gA + ko + (size_t)64 * Kdim, &sA[buf][2048 + ldsbase]);
    gload16(gB + ko, &sB[buf][ldsbase]);
    gload16(gB + ko + (size_t)64 * Kdim, &sB[buf][2048 + ldsbase]);
  };

  const int nk = Kdim / 32;
  int cur = 0;
  stage(0, 0);
  __syncthreads();
  for (int kt = 0; kt < nk; ++kt) {
    if (kt + 1 < nk) stage(cur ^ 1, kt + 1);
    bhalf8 af[4], bf[4];
#pragma unroll
    for (int m = 0; m < 4; ++m)
      af[m] = *(const bhalf8*)&sA[cur][(wr * 64 + m * 16 + lr) * 32 + lg * 8];
#pragma unroll
    for (int n = 0; n < 4; ++n)
      bf[n] = *(const bhalf8*)&sB[cur][(wc * 64 + n * 16 + lr) * 32 + lg * 8];
#pragma unroll
    for (int m = 0; m < 4; ++m)
#pragma unroll
      for (int n = 0; n < 4; ++n)
        acc[m][n] = __builtin_amdgcn_mfma_f32_16x16x32_bf16(af[m], bf[n], acc[m][n], 0, 0, 0);
    __syncthreads();
    cur ^= 1;
  }

#pragma unroll
  for (int m = 0; m < 4; ++m) {
#pragma unroll
    for (int n = 0; n < 4; ++n) {
      const int col = col0 + wc * 64 + n * 16 + lr;
      const int rowb = row0 + wr * 64 + m * 16 + lg * 4;
      if (MODE == 0) {
        u16* C = (u16*)Cout;
#pragma unroll
        for (int r = 0; r < 4; ++r)
          C[(size_t)(rowb + r) * Ndim + col] = f2bf(acc[m][n][r] * scale);
      } else if (MODE == 1) {
        // V^T layout: Vt[(b*1024 + col)][s], s = row % S, b = row / S; 4 rows contiguous
        u16* C = (u16*)Cout;
        const int bidx = rowb >> 11, s = rowb & (SS - 1);
        ushort4 pk;
        pk.x = f2bf(acc[m][n][0]); pk.y = f2bf(acc[m][n][1]);
        pk.z = f2bf(acc[m][n][2]); pk.w = f2bf(acc[m][n][3]);
        *(ushort4*)&C[((size_t)bidx * 1024 + col) * SS + s] = pk;
      } else {
        float* C = (float*)Cout;
#pragma unroll
        for (int r = 0; r < 4; ++r)
          C[(size_t)(rowb + r) * Ndim + col] = acc[m][n][r];
      }
    }
  }
}

// ---------------- flash attention ----------------
// grid (S/64, H, B), 256 threads = 4 waves, each wave owns 16 q-rows.
// Q pre-scaled by 1/8. K [B,S,D] bf16, Vt [B*H*64][S] bf16. Online softmax.
__global__ __launch_bounds__(256, 2) void k_attn(
    const u16* __restrict__ Q, const u16* __restrict__ K, const u16* __restrict__ Vt,
    u16* __restrict__ O, const int* __restrict__ valid_lens) {
  const int t = threadIdx.x;
  const int w = t >> 6, lane = t & 63;
  const int lr = lane & 15, lg = lane >> 4;
  const int h = blockIdx.y, b = blockIdx.z;
  const int q0 = blockIdx.x * 64 + w * 16;
  const int vl = valid_lens[b];

  __shared__ __attribute__((aligned(16))) u16 p_lds[4][16 * 72];  // per-wave, stride 72

  const u16* Qp = Q + ((size_t)(b * SS + q0 + lr)) * DD + h * DHD;
  const bhalf8 qf0 = *(const bhalf8*)(Qp + lg * 8);
  const bhalf8 qf1 = *(const bhalf8*)(Qp + 32 + lg * 8);

  const u16* Kp = K + ((size_t)b * SS) * DD + h * DHD;
  const u16* Vp = Vt + ((size_t)(b * HH + h) * DHD) * SS;

  float mrun[4], lrun[4];
  floatx4 o[4] = {};
#pragma unroll
  for (int r = 0; r < 4; ++r) { mrun[r] = -1e30f; lrun[r] = 0.f; }

  for (int sk0 = 0; sk0 < SS; sk0 += 64) {
    if (sk0 >= vl) break;  // uniform per block (vl depends only on b)
    floatx4 s[4];
#pragma unroll
    for (int c = 0; c < 4; ++c) {
      const u16* kp = Kp + (size_t)(sk0 + c * 16 + lr) * DD;
      bhalf8 kf0 = *(const bhalf8*)(kp + lg * 8);
      bhalf8 kf1 = *(const bhalf8*)(kp + 32 + lg * 8);
      floatx4 z = {0.f, 0.f, 0.f, 0.f};
      z = __builtin_amdgcn_mfma_f32_16x16x32_bf16(qf0, kf0, z, 0, 0, 0);
      s[c] = __builtin_amdgcn_mfma_f32_16x16x32_bf16(qf1, kf1, z, 0, 0, 0);
      if (sk0 + c * 16 + lr >= vl) {  // mask: col index fixed per lane for all 4 regs
        s[c][0] = -1e6f; s[c][1] = -1e6f; s[c][2] = -1e6f; s[c][3] = -1e6f;
      }
    }
    // online softmax over this 64-col block; row r lives in 16 lanes of same lg
    float tmax[4];
#pragma unroll
    for (int r = 0; r < 4; ++r) {
      tmax[r] = fmaxf(fmaxf(s[0][r], s[1][r]), fmaxf(s[2][r], s[3][r]));
#pragma unroll
      for (int off = 1; off < 16; off <<= 1)
        tmax[r] = fmaxf(tmax[r], __shfl_xor(tmax[r], off));
    }
    float rs[4] = {0.f, 0.f, 0.f, 0.f};
    u16 pb[4][4];
#pragma unroll
    for (int r = 0; r < 4; ++r) {
      const float nm = fmaxf(mrun[r], tmax[r]);
      const float sc = __expf(mrun[r] - nm);
      mrun[r] = nm;
      lrun[r] *= sc;
      o[0][r] *= sc; o[1][r] *= sc; o[2][r] *= sc; o[3][r] *= sc;
#pragma unroll
      for (int c = 0; c < 4; ++c) {
        const float p = __expf(s[c][r] - nm);
        rs[r] += p;
        pb[c][r] = f2bf(p);
      }
    }
#pragma unroll
    for (int r = 0; r < 4; ++r) {
#pragma unroll
      for (int off = 1; off < 16; off <<= 1)
        rs[r] += __shfl_xor(rs[r], off);
      lrun[r] += rs[r];
    }
    __syncthreads();  // previous iter's P reads drained before overwrite
#pragma unroll
    for (int c = 0; c < 4; ++c)
#pragma unroll
      for (int r = 0; r < 4; ++r)
        p_lds[w][(lg * 4 + r) * 72 + c * 16 + lr] = pb[c][r];
    __syncthreads();  // P visible for A-fragment reads
    const bhalf8 pa0 = *(const bhalf8*)&p_lds[w][lr * 72 + lg * 8];
    const bhalf8 pa1 = *(const bhalf8*)&p_lds[w][lr * 72 + 32 + lg * 8];
#pragma unroll
    for (int dt = 0; dt < 4; ++dt) {
      const u16* vp = Vp + (size_t)(dt * 16 + lr) * SS + sk0 + lg * 8;
      bhalf8 vf0 = *(const bhalf8*)(vp);
      bhalf8 vf1 = *(const bhalf8*)(vp + 32);
      o[dt] = __builtin_amdgcn_mfma_f32_16x16x32_bf16(pa0, vf0, o[dt], 0, 0, 0);
      o[dt] = __builtin_amdgcn_mfma_f32_16x16x32_bf16(pa1, vf1, o[dt], 0, 0, 0);
    }
  }
  u16* Op = O + ((size_t)(b * SS + q0)) * DD + h * DHD;
#pragma unroll
  for (int dt = 0; dt < 4; ++dt)
#pragma unroll
    for (int r = 0; r < 4; ++r) {
      const float val = o[dt][r] / lrun[r];
      Op[(size_t)(lg * 4 + r) * DD + dt * 16 + lr] = f2bf(val);
    }
}

extern "C" void kernel_launch(void* const* d_in, const int* in_sizes, int n_in,
                              void* d_out, int out_size, void* d_ws, size_t ws_size,
                              hipStream_t stream) {
  const float* q = (const float*)d_in[0];
  const float* k = (const float*)d_in[1];
  const float* v = (const float*)d_in[2];
  const int* vl = (const int*)d_in[3];
  const float* Wq = (const float*)d_in[4];
  const float* Wk = (const float*)d_in[5];
  const float* Wv = (const float*)d_in[6];
  const float* Wo = (const float*)d_in[7];

  char* ws = (char*)d_ws;
  // workspace layout (64 MiB total)
  u16* Xq  = (u16*)(ws + 0);          // 8 MiB each: bf16 inputs
  u16* Xk  = (u16*)(ws + 8388608);
  u16* Xv  = (u16*)(ws + 16777216);
  u16* Wtq = (u16*)(ws + 25165824);   // 2 MiB each: bf16 W^T
  u16* Wtk = (u16*)(ws + 27262976);
  u16* Wtv = (u16*)(ws + 29360128);
  u16* Wto = (u16*)(ws + 31457280);
  u16* Qb  = (u16*)(ws + 33554432);   // 8 MiB each: projected Q,K
  u16* Kb  = (u16*)(ws + 41943040);
  u16* Vtb = (u16*)(ws + 50331648);   // 8 MiB: head-transposed V
  u16* Ob  = (u16*)(ws + 58720256);   // 8 MiB: attention output (merged heads)

  const int n4 = (MM * DD) / 4;  // 1048576
  k_convert<<<4096, 256, 0, stream>>>(q, Xq, n4);
  k_convert<<<4096, 256, 0, stream>>>(k, Xk, n4);
  k_convert<<<4096, 256, 0, stream>>>(v, Xv, n4);

  dim3 tb(32, 8);
  k_transpose_w<<<dim3(32, 32), tb, 0, stream>>>(Wq, Wtq);
  k_transpose_w<<<dim3(32, 32), tb, 0, stream>>>(Wk, Wtk);
  k_transpose_w<<<dim3(32, 32), tb, 0, stream>>>(Wv, Wtv);
  k_transpose_w<<<dim3(32, 32), tb, 0, stream>>>(Wo, Wto);

  dim3 gg(DD / 128, MM / 128);  // (8, 32)
  k_gemm_bt<0><<<gg, 256, 0, stream>>>(Xq, Wtq, Qb, DD, DD, 0.125f);  // scale 1/sqrt(64) folded
  k_gemm_bt<0><<<gg, 256, 0, stream>>>(Xk, Wtk, Kb, DD, DD, 1.0f);
  k_gemm_bt<1><<<gg, 256, 0, stream>>>(Xv, Wtv, Vtb, DD, DD, 1.0f);

  k_attn<<<dim3(SS / 64, HH, BB), 256, 0, stream>>>(Qb, Kb, Vtb, Ob, vl);

  k_gemm_bt<2><<<gg, 256, 0, stream>>>(Ob, Wto, d_out, DD, DD, 1.0f);
}